// Round 1
// baseline (419.979 us; speedup 1.0000x reference)
//
#include <hip/hip_runtime.h>

#define B_ 2
#define NQ 2048
#define NK 2112
#define CD 1024
#define NH 16
#define HD 64

typedef unsigned short u16;
typedef unsigned int u32;
typedef __attribute__((ext_vector_type(8))) __bf16 bf16x8;
typedef __attribute__((ext_vector_type(4))) float f32x4;

#define GPTR(p) ((const __attribute__((address_space(1))) void*)(p))
#define LPTR(p) ((__attribute__((address_space(3))) void*)(p))
#define GLL16(g, l) __builtin_amdgcn_global_load_lds(GPTR(g), LPTR(l), 16, 0, 0)

__device__ __forceinline__ u16 f2bf(float f) {
  u32 u = __float_as_uint(f);
  u32 r = u + 0x7fffu + ((u >> 16) & 1u);
  return (u16)(r >> 16);
}
__device__ __forceinline__ float bf2f(u16 h) { return __uint_as_float(((u32)h) << 16); }

// ---------- f32 -> bf16 convert (x4 vectorized) ----------
__global__ void cvt_kernel(const float* __restrict__ src, u16* __restrict__ dst, int n4) {
  int i = blockIdx.x * 256 + threadIdx.x;
  if (i >= n4) return;
  float4 v = ((const float4*)src)[i];
  ushort4 o;
  o.x = f2bf(v.x); o.y = f2bf(v.y); o.z = f2bf(v.z); o.w = f2bf(v.w);
  ((ushort4*)dst)[i] = o;
}

// ---------- W (1024x1024 f32) -> Wt bf16 with Wt[n][k] = W[k][n] ----------
__global__ void wtrans_kernel(const float* __restrict__ W0, const float* __restrict__ W1,
                              const float* __restrict__ W2, const float* __restrict__ W3,
                              u16* __restrict__ T0, u16* __restrict__ T1,
                              u16* __restrict__ T2, u16* __restrict__ T3) {
  const float* src; u16* dst;
  switch (blockIdx.z) {
    case 0: src = W0; dst = T0; break;
    case 1: src = W1; dst = T1; break;
    case 2: src = W2; dst = T2; break;
    default: src = W3; dst = T3; break;
  }
  __shared__ u16 tile[32][33];
  int t = threadIdx.x;
  int r0 = blockIdx.y * 32, c0 = blockIdx.x * 32;
  int row = t >> 3, c4 = (t & 7) * 4;
  float4 v = *(const float4*)&src[(r0 + row) * 1024 + c0 + c4];
  tile[row][c4 + 0] = f2bf(v.x);
  tile[row][c4 + 1] = f2bf(v.y);
  tile[row][c4 + 2] = f2bf(v.z);
  tile[row][c4 + 3] = f2bf(v.w);
  __syncthreads();
  ushort4 o;
  o.x = tile[c4 + 0][row];
  o.y = tile[c4 + 1][row];
  o.z = tile[c4 + 2][row];
  o.w = tile[c4 + 3][row];
  *(ushort4*)&dst[(c0 + row) * 1024 + r0 + c4] = o;
}

// ---------- GEMM: C[M,1024] = A[M,1024] @ Bt[1024,1024]^T + bias ----------
// 128x128 tile, BK=32, 4 waves each 64x64 (4x4 MFMA tiles).
// EPI: 0 = bf16 row-major, 1 = f32 row-major, 2 = bf16 scattered to Vt[(b,h,dd),tok]
template <int EPI>
__global__ __launch_bounds__(256, 2) void gemm_bt(const u16* __restrict__ A,
                                                  const u16* __restrict__ Bt,
                                                  const float* __restrict__ bias,
                                                  void* __restrict__ Cout) {
  __shared__ u16 As[128 * 32];
  __shared__ u16 Bs[128 * 32];
  const int t = threadIdx.x;
  const int lane = t & 63, w = t >> 6;
  const int lc = lane & 15, lq = lane >> 4;
  const int m0 = blockIdx.y * 128, n0 = blockIdx.x * 128;
  const int wm = (w >> 1) * 64, wn = (w & 1) * 64;
  f32x4 acc[4][4] = {};
  const u16* ga = A + (m0 + (t >> 2)) * 1024 + (t & 3) * 8;
  const u16* gb = Bt + (n0 + (t >> 2)) * 1024 + (t & 3) * 8;
  char* lA = (char*)As + w * 1024;
  char* lB = (char*)Bs + w * 1024;
  for (int k0 = 0; k0 < 1024; k0 += 32) {
    if (k0) __syncthreads();
    GLL16(ga + k0, lA);
    GLL16(ga + 64 * 1024 + k0, lA + 4096);
    GLL16(gb + k0, lB);
    GLL16(gb + 64 * 1024 + k0, lB + 4096);
    __syncthreads();
    bf16x8 af[4], bf[4];
#pragma unroll
    for (int i = 0; i < 4; ++i) {
      af[i] = *(const bf16x8*)&As[(wm + i * 16 + lc) * 32 + lq * 8];
      bf[i] = *(const bf16x8*)&Bs[(wn + i * 16 + lc) * 32 + lq * 8];
    }
#pragma unroll
    for (int mi = 0; mi < 4; ++mi)
#pragma unroll
      for (int ni = 0; ni < 4; ++ni)
        acc[mi][ni] = __builtin_amdgcn_mfma_f32_16x16x32_bf16(af[mi], bf[ni], acc[mi][ni], 0, 0, 0);
  }
#pragma unroll
  for (int mi = 0; mi < 4; ++mi) {
#pragma unroll
    for (int ni = 0; ni < 4; ++ni) {
      int col = n0 + wn + ni * 16 + lc;
      float bv = bias[col];
#pragma unroll
      for (int r = 0; r < 4; ++r) {
        int row = m0 + wm + mi * 16 + lq * 4 + r;
        float v = acc[mi][ni][r] + bv;
        if (EPI == 1) {
          ((float*)Cout)[row * 1024 + col] = v;
        } else if (EPI == 0) {
          ((u16*)Cout)[row * 1024 + col] = f2bf(v);
        } else {
          int b = row >= NK ? 1 : 0;
          int tok = row - b * NK;
          int h = col >> 6, dd = col & 63;
          ((u16*)Cout)[((b * NH + h) * HD + dd) * NK + tok] = f2bf(v);
        }
      }
    }
  }
}

// ---------- in-place axial RoPE on bf16 (B*2048 rows x 512 pairs) ----------
__global__ void rope_kernel(u16* __restrict__ X, int batch_rows) {
  int idx = blockIdx.x * 256 + threadIdx.x;  // exactly 4096*512 threads
  int pc = idx & 511;                        // pair-column 0..511
  int lr = idx >> 9;                         // logical row 0..4095
  int bb = lr >> 11;
  int tok = lr & 2047;
  int row = bb * batch_rows + tok;
  int j = pc & 31;  // pair index within head (dim/2 = 32)
  int jj = (j < 16) ? j : j - 16;
  float pos = (j < 16) ? (float)(tok & 63) : (float)(tok >> 6);  // tx = n%64, ty = n/64
  float freq = exp2f((float)jj * -0.8304820237f);                // theta^(-jj/16)
  float ang = pos * freq;
  float s, c;
  __sincosf(ang, &s, &c);
  u32* p = (u32*)X + row * 512 + pc;
  u32 v = *p;
  float xe = bf2f((u16)(v & 0xffffu));
  float xo = bf2f((u16)(v >> 16));
  float oe = xe * c - xo * s;
  float oo = xe * s + xo * c;
  *p = (u32)f2bf(oe) | ((u32)f2bf(oo) << 16);
}

// ---------- flash attention ----------
// grid (16 qtiles, NH, B_); block 256 = 4 waves; Q tile 128 rows, K/V tiles 64 keys.
__global__ __launch_bounds__(256, 2) void attn_kernel(const u16* __restrict__ Qh,
                                                      const u16* __restrict__ Kh,
                                                      const u16* __restrict__ Vt,
                                                      u16* __restrict__ AO) {
  __shared__ u16 Qs[128 * 64];
  __shared__ u16 Ks[64 * 64];
  __shared__ u16 Vs[64 * 64];  // transposed: [dd][key]
  __shared__ u16 Ps[128 * 64];
  const int t = threadIdx.x;
  const int lane = t & 63, w = t >> 6;
  const int lc = lane & 15, lq = lane >> 4;
  const int qt = blockIdx.x, h = blockIdx.y, b = blockIdx.z;

  const u16* gq = Qh + (b * NQ + qt * 128 + (t >> 3)) * CD + h * HD + (t & 7) * 8;
  char* lQ = (char*)Qs + w * 1024;
#pragma unroll
  for (int i = 0; i < 4; ++i) GLL16(gq + i * 32 * CD, lQ + i * 4096);
  const u16* gk = Kh + (b * NK + (t >> 3)) * CD + h * HD + (t & 7) * 8;
  const u16* gv = Vt + ((b * NH + h) * HD + (t >> 3)) * NK + (t & 7) * 8;
  char* lK = (char*)Ks + w * 1024;
  char* lV = (char*)Vs + w * 1024;
  __syncthreads();

  bf16x8 qf[2][2];
#pragma unroll
  for (int mi = 0; mi < 2; ++mi)
#pragma unroll
    for (int kk = 0; kk < 2; ++kk)
      qf[mi][kk] = *(const bf16x8*)&Qs[(w * 32 + mi * 16 + lc) * 64 + kk * 32 + lq * 8];

  f32x4 oacc[2][4] = {};
  float mrow[2][4], lrow[2][4];
#pragma unroll
  for (int mi = 0; mi < 2; ++mi)
#pragma unroll
    for (int r = 0; r < 4; ++r) { mrow[mi][r] = -1e30f; lrow[mi][r] = 0.f; }
  const float SC = 0.18033688011112042f;  // (1/sqrt(64)) * log2(e)

  for (int j0 = 0; j0 < NK; j0 += 64) {
    __syncthreads();  // protect Ks/Vs from overwrite
    GLL16(gk + j0 * CD, lK);
    GLL16(gk + (j0 + 32) * CD, lK + 4096);
    GLL16(gv + j0, lV);
    GLL16(gv + 32 * NK + j0, lV + 4096);
    __syncthreads();

    f32x4 sacc[2][4] = {};
#pragma unroll
    for (int ni = 0; ni < 4; ++ni) {
      bf16x8 k0f = *(const bf16x8*)&Ks[(ni * 16 + lc) * 64 + lq * 8];
      bf16x8 k1f = *(const bf16x8*)&Ks[(ni * 16 + lc) * 64 + 32 + lq * 8];
#pragma unroll
      for (int mi = 0; mi < 2; ++mi) {
        sacc[mi][ni] = __builtin_amdgcn_mfma_f32_16x16x32_bf16(qf[mi][0], k0f, sacc[mi][ni], 0, 0, 0);
        sacc[mi][ni] = __builtin_amdgcn_mfma_f32_16x16x32_bf16(qf[mi][1], k1f, sacc[mi][ni], 0, 0, 0);
      }
    }
    // online softmax; lane owns rows mi*16 + lq*4 + r, cols lc across 16 lanes
#pragma unroll
    for (int mi = 0; mi < 2; ++mi) {
#pragma unroll
      for (int r = 0; r < 4; ++r) {
        float mx = fmaxf(fmaxf(sacc[mi][0][r], sacc[mi][1][r]),
                         fmaxf(sacc[mi][2][r], sacc[mi][3][r]));
#pragma unroll
        for (int d = 1; d < 16; d <<= 1) mx = fmaxf(mx, __shfl_xor(mx, d, 64));
        mx *= SC;
        float mnew = fmaxf(mrow[mi][r], mx);
        float alpha = exp2f(mrow[mi][r] - mnew);
        mrow[mi][r] = mnew;
        float rs = 0.f;
#pragma unroll
        for (int ni = 0; ni < 4; ++ni) {
          float p = exp2f(sacc[mi][ni][r] * SC - mnew);
          sacc[mi][ni][r] = p;
          rs += p;
        }
#pragma unroll
        for (int d = 1; d < 16; d <<= 1) rs += __shfl_xor(rs, d, 64);
        lrow[mi][r] = lrow[mi][r] * alpha + rs;
#pragma unroll
        for (int di = 0; di < 4; ++di) oacc[mi][di][r] *= alpha;
      }
    }
    // P: C-layout regs -> LDS (A-layout source for PV); wave-private region
#pragma unroll
    for (int mi = 0; mi < 2; ++mi)
#pragma unroll
      for (int ni = 0; ni < 4; ++ni)
#pragma unroll
        for (int r = 0; r < 4; ++r)
          Ps[(w * 32 + mi * 16 + lq * 4 + r) * 64 + ni * 16 + lc] = f2bf(sacc[mi][ni][r]);
#pragma unroll
    for (int kc = 0; kc < 2; ++kc) {
      bf16x8 pf[2], vf[4];
#pragma unroll
      for (int mi = 0; mi < 2; ++mi)
        pf[mi] = *(const bf16x8*)&Ps[(w * 32 + mi * 16 + lc) * 64 + kc * 32 + lq * 8];
#pragma unroll
      for (int di = 0; di < 4; ++di)
        vf[di] = *(const bf16x8*)&Vs[(di * 16 + lc) * 64 + kc * 32 + lq * 8];
#pragma unroll
      for (int mi = 0; mi < 2; ++mi)
#pragma unroll
        for (int di = 0; di < 4; ++di)
          oacc[mi][di] = __builtin_amdgcn_mfma_f32_16x16x32_bf16(pf[mi], vf[di], oacc[mi][di], 0, 0, 0);
    }
  }
#pragma unroll
  for (int mi = 0; mi < 2; ++mi)
#pragma unroll
    for (int di = 0; di < 4; ++di)
#pragma unroll
      for (int r = 0; r < 4; ++r) {
        int row = qt * 128 + w * 32 + mi * 16 + lq * 4 + r;
        int col = h * HD + di * 16 + lc;
        float v = oacc[mi][di][r] / lrow[mi][r];
        AO[(b * NQ + row) * CD + col] = f2bf(v);
      }
}

extern "C" void kernel_launch(void* const* d_in, const int* in_sizes, int n_in,
                              void* d_out, int out_size, void* d_ws, size_t ws_size,
                              hipStream_t stream) {
  const float* q  = (const float*)d_in[0];
  const float* k  = (const float*)d_in[1];
  const float* v  = (const float*)d_in[2];
  const float* Wq = (const float*)d_in[3];
  const float* bq = (const float*)d_in[4];
  const float* Wk = (const float*)d_in[5];
  const float* bk = (const float*)d_in[6];
  const float* Wv = (const float*)d_in[7];
  const float* bv = (const float*)d_in[8];
  const float* Wo = (const float*)d_in[9];
  const float* bo = (const float*)d_in[10];

  char* ws = (char*)d_ws;
  size_t off = 0;
  auto alloc = [&](size_t bytes) {
    char* p = ws + off;
    off += (bytes + 255) & ~(size_t)255;
    return p;
  };
  u16* qb  = (u16*)alloc((size_t)B_ * NQ * CD * 2);
  u16* kb  = (u16*)alloc((size_t)B_ * NK * CD * 2);
  u16* vb  = (u16*)alloc((size_t)B_ * NK * CD * 2);
  u16* wqt = (u16*)alloc((size_t)CD * CD * 2);
  u16* wkt = (u16*)alloc((size_t)CD * CD * 2);
  u16* wvt = (u16*)alloc((size_t)CD * CD * 2);
  u16* wot = (u16*)alloc((size_t)CD * CD * 2);
  u16* Qh  = (u16*)alloc((size_t)B_ * NQ * CD * 2);
  u16* Kh  = (u16*)alloc((size_t)B_ * NK * CD * 2);
  u16* Vt  = (u16*)alloc((size_t)B_ * NK * CD * 2);
  u16* AO  = (u16*)alloc((size_t)B_ * NQ * CD * 2);

  cvt_kernel<<<(B_ * NQ * CD / 4 + 255) / 256, 256, 0, stream>>>(q, qb, B_ * NQ * CD / 4);
  cvt_kernel<<<(B_ * NK * CD / 4 + 255) / 256, 256, 0, stream>>>(k, kb, B_ * NK * CD / 4);
  cvt_kernel<<<(B_ * NK * CD / 4 + 255) / 256, 256, 0, stream>>>(v, vb, B_ * NK * CD / 4);
  wtrans_kernel<<<dim3(32, 32, 4), 256, 0, stream>>>(Wq, Wk, Wv, Wo, wqt, wkt, wvt, wot);
  gemm_bt<0><<<dim3(8, 32), 256, 0, stream>>>(qb, wqt, bq, Qh);
  gemm_bt<0><<<dim3(8, 33), 256, 0, stream>>>(kb, wkt, bk, Kh);
  gemm_bt<2><<<dim3(8, 33), 256, 0, stream>>>(vb, wvt, bv, Vt);
  rope_kernel<<<8192, 256, 0, stream>>>(Qh, NQ);
  rope_kernel<<<8192, 256, 0, stream>>>(Kh, NK);
  attn_kernel<<<dim3(16, NH, B_), 256, 0, stream>>>(Qh, Kh, Vt, AO);
  gemm_bt<1><<<dim3(8, 32), 256, 0, stream>>>(AO, wot, bo, d_out);
}

// Round 2
// 349.376 us; speedup vs baseline: 1.2021x; 1.2021x over previous
//
#include <hip/hip_runtime.h>

#define B_ 2
#define NQ 2048
#define NK 2112
#define CD 1024
#define NH 16
#define HD 64

typedef unsigned short u16;
typedef unsigned int u32;
typedef __attribute__((ext_vector_type(8))) __bf16 bf16x8;
typedef __attribute__((ext_vector_type(4))) float f32x4;

#define GPTR(p) ((const __attribute__((address_space(1))) void*)(p))
#define LPTR(p) ((__attribute__((address_space(3))) void*)(p))
#define GLL16(g, l) __builtin_amdgcn_global_load_lds(GPTR(g), LPTR(l), 16, 0, 0)

__device__ __forceinline__ u16 f2bf(float f) {
  u32 u = __float_as_uint(f);
  u32 r = u + 0x7fffu + ((u >> 16) & 1u);
  return (u16)(r >> 16);
}
__device__ __forceinline__ float bf2f(u16 h) { return __uint_as_float(((u32)h) << 16); }

// ---------- f32 -> bf16 convert, all three inputs in one dispatch ----------
__global__ void cvt3_kernel(const float* __restrict__ q, const float* __restrict__ k,
                            const float* __restrict__ v, u16* __restrict__ qb,
                            u16* __restrict__ kb, u16* __restrict__ vb) {
  int z = blockIdx.y;
  const float* src = (z == 0) ? q : (z == 1) ? k : v;
  u16* dst = (z == 0) ? qb : (z == 1) ? kb : vb;
  int n4 = (z == 0) ? (B_ * NQ * CD / 4) : (B_ * NK * CD / 4);
  int i = blockIdx.x * 256 + threadIdx.x;
  if (i >= n4) return;
  float4 vv = ((const float4*)src)[i];
  ushort4 o;
  o.x = f2bf(vv.x); o.y = f2bf(vv.y); o.z = f2bf(vv.z); o.w = f2bf(vv.w);
  ((ushort4*)dst)[i] = o;
}

// ---------- W (1024x1024 f32) -> Wt bf16 with Wt[n][k] = W[k][n] ----------
__global__ void wtrans_kernel(const float* __restrict__ W0, const float* __restrict__ W1,
                              const float* __restrict__ W2, const float* __restrict__ W3,
                              u16* __restrict__ T0, u16* __restrict__ T1,
                              u16* __restrict__ T2, u16* __restrict__ T3) {
  const float* src; u16* dst;
  switch (blockIdx.z) {
    case 0: src = W0; dst = T0; break;
    case 1: src = W1; dst = T1; break;
    case 2: src = W2; dst = T2; break;
    default: src = W3; dst = T3; break;
  }
  __shared__ u16 tile[32][33];
  int t = threadIdx.x;
  int r0 = blockIdx.y * 32, c0 = blockIdx.x * 32;
  int row = t >> 3, c4 = (t & 7) * 4;
  float4 v = *(const float4*)&src[(r0 + row) * 1024 + c0 + c4];
  tile[row][c4 + 0] = f2bf(v.x);
  tile[row][c4 + 1] = f2bf(v.y);
  tile[row][c4 + 2] = f2bf(v.z);
  tile[row][c4 + 3] = f2bf(v.w);
  __syncthreads();
  ushort4 o;
  o.x = tile[c4 + 0][row];
  o.y = tile[c4 + 1][row];
  o.z = tile[c4 + 2][row];
  o.w = tile[c4 + 3][row];
  *(ushort4*)&dst[(c0 + row) * 1024 + r0 + c4] = o;
}

// ---------- fused QKV projection GEMM + RoPE epilogue ----------
// C[M,1024] = A[M,1024] @ Bt[1024,1024]^T + bias, 128x128 tile, BK=32.
// z=0: Q (rope all rows, row-major out), z=1: K (rope tok<2048, row-major out),
// z=2: V (no rope, scatter to Vt[(b,h,dd),tok]).
__global__ __launch_bounds__(256, 2) void gemm_qkv(
    const u16* __restrict__ qb, const u16* __restrict__ kb, const u16* __restrict__ vb,
    const u16* __restrict__ wqt, const u16* __restrict__ wkt, const u16* __restrict__ wvt,
    const float* __restrict__ bq, const float* __restrict__ bk, const float* __restrict__ bv,
    u16* __restrict__ Qh, u16* __restrict__ Kh, u16* __restrict__ Vt) {
  const int z = blockIdx.z;
  if (z == 0 && blockIdx.y >= 32) return;  // Q has 4096 rows only
  const u16* A = (z == 0) ? qb : (z == 1) ? kb : vb;
  const u16* Bt = (z == 0) ? wqt : (z == 1) ? wkt : wvt;
  const float* bias = (z == 0) ? bq : (z == 1) ? bk : bv;
  const int batch_rows = (z == 0) ? NQ : NK;

  __shared__ u16 As[128 * 32];
  __shared__ u16 Bs[128 * 32];
  const int t = threadIdx.x;
  const int lane = t & 63, w = t >> 6;
  const int lc = lane & 15, lq = lane >> 4;
  const int m0 = blockIdx.y * 128, n0 = blockIdx.x * 128;
  const int wm = (w >> 1) * 64, wn = (w & 1) * 64;
  f32x4 acc[4][4] = {};
  const u16* ga = A + (m0 + (t >> 2)) * 1024 + (t & 3) * 8;
  const u16* gb = Bt + (n0 + (t >> 2)) * 1024 + (t & 3) * 8;
  char* lA = (char*)As + w * 1024;
  char* lB = (char*)Bs + w * 1024;
  for (int k0 = 0; k0 < 1024; k0 += 32) {
    if (k0) __syncthreads();
    GLL16(ga + k0, lA);
    GLL16(ga + 64 * 1024 + k0, lA + 4096);
    GLL16(gb + k0, lB);
    GLL16(gb + 64 * 1024 + k0, lB + 4096);
    __syncthreads();
    bf16x8 af[4], bf[4];
#pragma unroll
    for (int i = 0; i < 4; ++i) {
      af[i] = *(const bf16x8*)&As[(wm + i * 16 + lc) * 32 + lq * 8];
      bf[i] = *(const bf16x8*)&Bs[(wn + i * 16 + lc) * 32 + lq * 8];
    }
#pragma unroll
    for (int mi = 0; mi < 4; ++mi)
#pragma unroll
      for (int ni = 0; ni < 4; ++ni)
        acc[mi][ni] = __builtin_amdgcn_mfma_f32_16x16x32_bf16(af[mi], bf[ni], acc[mi][ni], 0, 0, 0);
  }
#pragma unroll
  for (int mi = 0; mi < 4; ++mi) {
#pragma unroll
    for (int ni = 0; ni < 4; ++ni) {
      int col = n0 + wn + ni * 16 + lc;
      float bv_ = bias[col];
      // rope constants for this column (pair index j = (col&63)>>1)
      int j = (col >> 1) & 31;
      bool jlow = j < 16;
      float freq = exp2f((float)(jlow ? j : j - 16) * -0.8304820237f);
#pragma unroll
      for (int r = 0; r < 4; ++r) {
        int row = m0 + wm + mi * 16 + lq * 4 + r;
        float v = acc[mi][ni][r] + bv_;
        if (z < 2) {
          int bb = row >= batch_rows ? 1 : 0;
          int tok = row - bb * batch_rows;
          float p = __shfl_xor(v, 1, 64);  // rope partner (col^1), same row
          float ov = v;
          if (tok < 2048) {
            float pos = jlow ? (float)(tok & 63) : (float)(tok >> 6);
            float s, c;
            __sincosf(pos * freq, &s, &c);
            ov = ((col & 1) == 0) ? (v * c - p * s) : (p * s + v * c);
          }
          ((z == 0) ? Qh : Kh)[row * 1024 + col] = f2bf(ov);
        } else {
          int bb = row >= NK ? 1 : 0;
          int tok = row - bb * NK;
          int h = col >> 6, dd = col & 63;
          Vt[((bb * NH + h) * HD + dd) * NK + tok] = f2bf(v);
        }
      }
    }
  }
}

// ---------- O projection: f32 out ----------
__global__ __launch_bounds__(256, 2) void gemm_o(const u16* __restrict__ A,
                                                 const u16* __restrict__ Bt,
                                                 const float* __restrict__ bias,
                                                 float* __restrict__ Cout) {
  __shared__ u16 As[128 * 32];
  __shared__ u16 Bs[128 * 32];
  const int t = threadIdx.x;
  const int lane = t & 63, w = t >> 6;
  const int lc = lane & 15, lq = lane >> 4;
  const int m0 = blockIdx.y * 128, n0 = blockIdx.x * 128;
  const int wm = (w >> 1) * 64, wn = (w & 1) * 64;
  f32x4 acc[4][4] = {};
  const u16* ga = A + (m0 + (t >> 2)) * 1024 + (t & 3) * 8;
  const u16* gb = Bt + (n0 + (t >> 2)) * 1024 + (t & 3) * 8;
  char* lA = (char*)As + w * 1024;
  char* lB = (char*)Bs + w * 1024;
  for (int k0 = 0; k0 < 1024; k0 += 32) {
    if (k0) __syncthreads();
    GLL16(ga + k0, lA);
    GLL16(ga + 64 * 1024 + k0, lA + 4096);
    GLL16(gb + k0, lB);
    GLL16(gb + 64 * 1024 + k0, lB + 4096);
    __syncthreads();
    bf16x8 af[4], bf[4];
#pragma unroll
    for (int i = 0; i < 4; ++i) {
      af[i] = *(const bf16x8*)&As[(wm + i * 16 + lc) * 32 + lq * 8];
      bf[i] = *(const bf16x8*)&Bs[(wn + i * 16 + lc) * 32 + lq * 8];
    }
#pragma unroll
    for (int mi = 0; mi < 4; ++mi)
#pragma unroll
      for (int ni = 0; ni < 4; ++ni)
        acc[mi][ni] = __builtin_amdgcn_mfma_f32_16x16x32_bf16(af[mi], bf[ni], acc[mi][ni], 0, 0, 0);
  }
#pragma unroll
  for (int mi = 0; mi < 4; ++mi)
#pragma unroll
    for (int ni = 0; ni < 4; ++ni) {
      int col = n0 + wn + ni * 16 + lc;
      float bv = bias[col];
#pragma unroll
      for (int r = 0; r < 4; ++r) {
        int row = m0 + wm + mi * 16 + lq * 4 + r;
        Cout[row * 1024 + col] = acc[mi][ni][r] + bv;
      }
    }
}

// ---------- flash attention, conflict-free padded LDS (stride 72 u16) ----------
// grid (16 qtiles, NH, B_); block 256 = 4 waves; Q tile 128 rows, K/V tiles 64 keys.
// Ps aliases Qs (Q frags held in registers); K/V software-pipelined via VGPRs.
#define LSTR 72
__global__ __launch_bounds__(256, 2) void attn_kernel(const u16* __restrict__ Qh,
                                                      const u16* __restrict__ Kh,
                                                      const u16* __restrict__ Vt,
                                                      u16* __restrict__ AO) {
  __shared__ u16 QPs[128 * LSTR];  // Q staging, then P round-trip (wave-private rows)
  __shared__ u16 Ks[64 * LSTR];
  __shared__ u16 Vs[64 * LSTR];  // transposed: [dd][key]
  const int t = threadIdx.x;
  const int lane = t & 63, w = t >> 6;
  const int lc = lane & 15, lq = lane >> 4;
  const int rr = lane >> 3, s = lane & 7;
  const int qt = blockIdx.x, h = blockIdx.y, b = blockIdx.z;

  // ---- stage Q into wave-private LDS rows (no barrier needed) ----
  {
    const u16* gq = Qh + (b * NQ + qt * 128 + w * 32 + rr) * CD + h * HD + s * 8;
    u16* lqp = &QPs[(w * 32 + rr) * LSTR + s * 8];
#pragma unroll
    for (int i = 0; i < 4; ++i)
      *(uint4*)(lqp + i * 8 * LSTR) = *(const uint4*)(gq + i * 8 * CD);
  }
  bf16x8 qf[2][2];
#pragma unroll
  for (int mi = 0; mi < 2; ++mi)
#pragma unroll
    for (int kk = 0; kk < 2; ++kk)
      qf[mi][kk] = *(const bf16x8*)&QPs[(w * 32 + mi * 16 + lc) * LSTR + kk * 32 + lq * 8];

  // ---- K/V pipeline registers ----
  const u16* gK = Kh + (b * NK + w * 16 + rr) * CD + h * HD + s * 8;
  const u16* gV = Vt + ((b * NH + h) * HD + w * 16 + rr) * NK + s * 8;
  uint4 kreg0, kreg1, vreg0, vreg1;
  kreg0 = *(const uint4*)(gK);
  kreg1 = *(const uint4*)(gK + 8 * CD);
  vreg0 = *(const uint4*)(gV);
  vreg1 = *(const uint4*)(gV + 8 * NK);

  f32x4 oacc[2][4] = {};
  float mrow[2][4], lrow[2][4];
#pragma unroll
  for (int mi = 0; mi < 2; ++mi)
#pragma unroll
    for (int r = 0; r < 4; ++r) { mrow[mi][r] = -1e30f; lrow[mi][r] = 0.f; }
  const float SC = 0.18033688011112042f;  // (1/sqrt(64)) * log2(e)

  for (int j0 = 0; j0 < NK; j0 += 64) {
    __syncthreads();  // everyone done reading previous Ks/Vs
    *(uint4*)&Ks[(w * 16 + rr) * LSTR + s * 8] = kreg0;
    *(uint4*)&Ks[(w * 16 + 8 + rr) * LSTR + s * 8] = kreg1;
    *(uint4*)&Vs[(w * 16 + rr) * LSTR + s * 8] = vreg0;
    *(uint4*)&Vs[(w * 16 + 8 + rr) * LSTR + s * 8] = vreg1;
    __syncthreads();
    if (j0 + 64 < NK) {  // prefetch next tile, in flight during compute
      kreg0 = *(const uint4*)(gK + (j0 + 64) * CD);
      kreg1 = *(const uint4*)(gK + (j0 + 64) * CD + 8 * CD);
      vreg0 = *(const uint4*)(gV + j0 + 64);
      vreg1 = *(const uint4*)(gV + 8 * NK + j0 + 64);
    }

    f32x4 sacc[2][4] = {};
#pragma unroll
    for (int ni = 0; ni < 4; ++ni) {
      bf16x8 k0f = *(const bf16x8*)&Ks[(ni * 16 + lc) * LSTR + lq * 8];
      bf16x8 k1f = *(const bf16x8*)&Ks[(ni * 16 + lc) * LSTR + 32 + lq * 8];
#pragma unroll
      for (int mi = 0; mi < 2; ++mi) {
        sacc[mi][ni] = __builtin_amdgcn_mfma_f32_16x16x32_bf16(qf[mi][0], k0f, sacc[mi][ni], 0, 0, 0);
        sacc[mi][ni] = __builtin_amdgcn_mfma_f32_16x16x32_bf16(qf[mi][1], k1f, sacc[mi][ni], 0, 0, 0);
      }
    }
    // online softmax; lane owns rows mi*16 + lq*4 + r, cols ni*16 + lc
#pragma unroll
    for (int mi = 0; mi < 2; ++mi) {
#pragma unroll
      for (int r = 0; r < 4; ++r) {
        float mx = fmaxf(fmaxf(sacc[mi][0][r], sacc[mi][1][r]),
                         fmaxf(sacc[mi][2][r], sacc[mi][3][r]));
#pragma unroll
        for (int d = 1; d < 16; d <<= 1) mx = fmaxf(mx, __shfl_xor(mx, d, 64));
        mx *= SC;
        float mnew = fmaxf(mrow[mi][r], mx);
        float alpha = exp2f(mrow[mi][r] - mnew);
        mrow[mi][r] = mnew;
        float rs = 0.f;
#pragma unroll
        for (int ni = 0; ni < 4; ++ni) {
          float p = exp2f(sacc[mi][ni][r] * SC - mnew);
          sacc[mi][ni][r] = p;
          rs += p;
        }
#pragma unroll
        for (int d = 1; d < 16; d <<= 1) rs += __shfl_xor(rs, d, 64);
        lrow[mi][r] = lrow[mi][r] * alpha + rs;
#pragma unroll
        for (int di = 0; di < 4; ++di) oacc[mi][di][r] *= alpha;
      }
    }
    // P: C-layout regs -> LDS (A-layout source for PV); wave-private rows of QPs
#pragma unroll
    for (int mi = 0; mi < 2; ++mi)
#pragma unroll
      for (int ni = 0; ni < 4; ++ni)
#pragma unroll
        for (int r = 0; r < 4; ++r)
          QPs[(w * 32 + mi * 16 + lq * 4 + r) * LSTR + ni * 16 + lc] = f2bf(sacc[mi][ni][r]);
#pragma unroll
    for (int kc = 0; kc < 2; ++kc) {
      bf16x8 pf[2], vf[4];
#pragma unroll
      for (int mi = 0; mi < 2; ++mi)
        pf[mi] = *(const bf16x8*)&QPs[(w * 32 + mi * 16 + lc) * LSTR + kc * 32 + lq * 8];
#pragma unroll
      for (int di = 0; di < 4; ++di)
        vf[di] = *(const bf16x8*)&Vs[(di * 16 + lc) * LSTR + kc * 32 + lq * 8];
#pragma unroll
      for (int mi = 0; mi < 2; ++mi)
#pragma unroll
        for (int di = 0; di < 4; ++di)
          oacc[mi][di] = __builtin_amdgcn_mfma_f32_16x16x32_bf16(pf[mi], vf[di], oacc[mi][di], 0, 0, 0);
    }
  }
#pragma unroll
  for (int mi = 0; mi < 2; ++mi)
#pragma unroll
    for (int di = 0; di < 4; ++di)
#pragma unroll
      for (int r = 0; r < 4; ++r) {
        int row = qt * 128 + w * 32 + mi * 16 + lq * 4 + r;
        int col = h * HD + di * 16 + lc;
        float v = oacc[mi][di][r] / lrow[mi][r];
        AO[(b * NQ + row) * CD + col] = f2bf(v);
      }
}

extern "C" void kernel_launch(void* const* d_in, const int* in_sizes, int n_in,
                              void* d_out, int out_size, void* d_ws, size_t ws_size,
                              hipStream_t stream) {
  const float* q  = (const float*)d_in[0];
  const float* k  = (const float*)d_in[1];
  const float* v  = (const float*)d_in[2];
  const float* Wq = (const float*)d_in[3];
  const float* bq = (const float*)d_in[4];
  const float* Wk = (const float*)d_in[5];
  const float* bk = (const float*)d_in[6];
  const float* Wv = (const float*)d_in[7];
  const float* bv = (const float*)d_in[8];
  const float* Wo = (const float*)d_in[9];
  const float* bo = (const float*)d_in[10];

  char* ws = (char*)d_ws;
  size_t off = 0;
  auto alloc = [&](size_t bytes) {
    char* p = ws + off;
    off += (bytes + 255) & ~(size_t)255;
    return p;
  };
  u16* qb  = (u16*)alloc((size_t)B_ * NQ * CD * 2);
  u16* kb  = (u16*)alloc((size_t)B_ * NK * CD * 2);
  u16* vb  = (u16*)alloc((size_t)B_ * NK * CD * 2);
  u16* wqt = (u16*)alloc((size_t)CD * CD * 2);
  u16* wkt = (u16*)alloc((size_t)CD * CD * 2);
  u16* wvt = (u16*)alloc((size_t)CD * CD * 2);
  u16* wot = (u16*)alloc((size_t)CD * CD * 2);
  u16* Qh  = (u16*)alloc((size_t)B_ * NQ * CD * 2);
  u16* Kh  = (u16*)alloc((size_t)B_ * NK * CD * 2);
  u16* Vt  = (u16*)alloc((size_t)B_ * NK * CD * 2);
  u16* AO  = (u16*)alloc((size_t)B_ * NQ * CD * 2);

  cvt3_kernel<<<dim3(4224, 3), 256, 0, stream>>>(q, k, v, qb, kb, vb);
  wtrans_kernel<<<dim3(32, 32, 4), 256, 0, stream>>>(Wq, Wk, Wv, Wo, wqt, wkt, wvt, wot);
  gemm_qkv<<<dim3(8, 33, 3), 256, 0, stream>>>(qb, kb, vb, wqt, wkt, wvt, bq, bk, bv, Qh, Kh, Vt);
  attn_kernel<<<dim3(16, NH, B_), 256, 0, stream>>>(Qh, Kh, Vt, AO);
  gemm_o<<<dim3(8, 32), 256, 0, stream>>>(AO, wot, bo, (float*)d_out);
}

// Round 3
// 266.506 us; speedup vs baseline: 1.5759x; 1.3109x over previous
//
#include <hip/hip_runtime.h>

#define B_ 2
#define NQ 2048
#define NK 2112
#define CD 1024
#define NH 16
#define HD 64

typedef unsigned short u16;
typedef unsigned int u32;
typedef __attribute__((ext_vector_type(8))) __bf16 bf16x8;
typedef __attribute__((ext_vector_type(4))) float f32x4;

#define GPTR(p) ((const __attribute__((address_space(1))) void*)(p))
#define LPTR(p) ((__attribute__((address_space(3))) void*)(p))
#define GLL16(g, l) __builtin_amdgcn_global_load_lds(GPTR(g), LPTR(l), 16, 0, 0)

__device__ __forceinline__ u16 f2bf(float f) {
  u32 u = __float_as_uint(f);
  u32 r = u + 0x7fffu + ((u >> 16) & 1u);
  return (u16)(r >> 16);
}
// positive finite values only (softmax probs): round-to-nearest w/o tie-to-even
__device__ __forceinline__ u16 f2bf_pos(float f) {
  return (u16)((__float_as_uint(f) + 0x8000u) >> 16);
}
__device__ __forceinline__ float bf2f(u16 h) { return __uint_as_float(((u32)h) << 16); }

// ---------- f32 -> bf16 convert, all three inputs in one dispatch ----------
__global__ void cvt3_kernel(const float* __restrict__ q, const float* __restrict__ k,
                            const float* __restrict__ v, u16* __restrict__ qb,
                            u16* __restrict__ kb, u16* __restrict__ vb) {
  int z = blockIdx.y;
  const float* src = (z == 0) ? q : (z == 1) ? k : v;
  u16* dst = (z == 0) ? qb : (z == 1) ? kb : vb;
  int n4 = (z == 0) ? (B_ * NQ * CD / 4) : (B_ * NK * CD / 4);
  int i = blockIdx.x * 256 + threadIdx.x;
  if (i >= n4) return;
  float4 vv = ((const float4*)src)[i];
  ushort4 o;
  o.x = f2bf(vv.x); o.y = f2bf(vv.y); o.z = f2bf(vv.z); o.w = f2bf(vv.w);
  ((ushort4*)dst)[i] = o;
}

// ---------- W (1024x1024 f32) -> Wt bf16 with Wt[n][k] = W[k][n] ----------
__global__ void wtrans_kernel(const float* __restrict__ W0, const float* __restrict__ W1,
                              const float* __restrict__ W2, const float* __restrict__ W3,
                              u16* __restrict__ T0, u16* __restrict__ T1,
                              u16* __restrict__ T2, u16* __restrict__ T3) {
  const float* src; u16* dst;
  switch (blockIdx.z) {
    case 0: src = W0; dst = T0; break;
    case 1: src = W1; dst = T1; break;
    case 2: src = W2; dst = T2; break;
    default: src = W3; dst = T3; break;
  }
  __shared__ u16 tile[32][33];
  int t = threadIdx.x;
  int r0 = blockIdx.y * 32, c0 = blockIdx.x * 32;
  int row = t >> 3, c4 = (t & 7) * 4;
  float4 v = *(const float4*)&src[(r0 + row) * 1024 + c0 + c4];
  tile[row][c4 + 0] = f2bf(v.x);
  tile[row][c4 + 1] = f2bf(v.y);
  tile[row][c4 + 2] = f2bf(v.z);
  tile[row][c4 + 3] = f2bf(v.w);
  __syncthreads();
  ushort4 o;
  o.x = tile[c4 + 0][row];
  o.y = tile[c4 + 1][row];
  o.z = tile[c4 + 2][row];
  o.w = tile[c4 + 3][row];
  *(ushort4*)&dst[(c0 + row) * 1024 + r0 + c4] = o;
}

// (1/sqrt(64)) * log2(e) — folded into the Q projection output
#define SC 0.18033688011112042f

// ---------- fused QKV projection GEMM + RoPE epilogue ----------
// z=0: Q (rope, *SC, row-major out), z=1: K (rope tok<2048, row-major out),
// z=2: V (no rope, scatter to Vt[(b,h,dd),tok]).
__global__ __launch_bounds__(256, 2) void gemm_qkv(
    const u16* __restrict__ qb, const u16* __restrict__ kb, const u16* __restrict__ vb,
    const u16* __restrict__ wqt, const u16* __restrict__ wkt, const u16* __restrict__ wvt,
    const float* __restrict__ bq, const float* __restrict__ bk, const float* __restrict__ bv,
    u16* __restrict__ Qh, u16* __restrict__ Kh, u16* __restrict__ Vt) {
  const int z = blockIdx.z;
  if (z == 0 && blockIdx.y >= 32) return;  // Q has 4096 rows only
  const u16* A = (z == 0) ? qb : (z == 1) ? kb : vb;
  const u16* Bt = (z == 0) ? wqt : (z == 1) ? wkt : wvt;
  const float* bias = (z == 0) ? bq : (z == 1) ? bk : bv;
  const int batch_rows = (z == 0) ? NQ : NK;

  __shared__ u16 As[128 * 32];
  __shared__ u16 Bs[128 * 32];
  const int t = threadIdx.x;
  const int lane = t & 63, w = t >> 6;
  const int lc = lane & 15, lq = lane >> 4;
  const int m0 = blockIdx.y * 128, n0 = blockIdx.x * 128;
  const int wm = (w >> 1) * 64, wn = (w & 1) * 64;
  f32x4 acc[4][4] = {};
  const u16* ga = A + (m0 + (t >> 2)) * 1024 + (t & 3) * 8;
  const u16* gb = Bt + (n0 + (t >> 2)) * 1024 + (t & 3) * 8;
  char* lA = (char*)As + w * 1024;
  char* lB = (char*)Bs + w * 1024;
  for (int k0 = 0; k0 < 1024; k0 += 32) {
    if (k0) __syncthreads();
    GLL16(ga + k0, lA);
    GLL16(ga + 64 * 1024 + k0, lA + 4096);
    GLL16(gb + k0, lB);
    GLL16(gb + 64 * 1024 + k0, lB + 4096);
    __syncthreads();
    bf16x8 af[4], bf[4];
#pragma unroll
    for (int i = 0; i < 4; ++i) {
      af[i] = *(const bf16x8*)&As[(wm + i * 16 + lc) * 32 + lq * 8];
      bf[i] = *(const bf16x8*)&Bs[(wn + i * 16 + lc) * 32 + lq * 8];
    }
#pragma unroll
    for (int mi = 0; mi < 4; ++mi)
#pragma unroll
      for (int ni = 0; ni < 4; ++ni)
        acc[mi][ni] = __builtin_amdgcn_mfma_f32_16x16x32_bf16(af[mi], bf[ni], acc[mi][ni], 0, 0, 0);
  }
#pragma unroll
  for (int mi = 0; mi < 4; ++mi) {
#pragma unroll
    for (int ni = 0; ni < 4; ++ni) {
      int col = n0 + wn + ni * 16 + lc;
      float bv_ = bias[col];
      int j = (col >> 1) & 31;  // pair index within head
      bool jlow = j < 16;
      float freq = exp2f((float)(jlow ? j : j - 16) * -0.8304820237f);
#pragma unroll
      for (int r = 0; r < 4; ++r) {
        int row = m0 + wm + mi * 16 + lq * 4 + r;
        float v = acc[mi][ni][r] + bv_;
        if (z < 2) {
          int bb = row >= batch_rows ? 1 : 0;
          int tok = row - bb * batch_rows;
          float p = __shfl_xor(v, 1, 64);  // rope partner (col^1), same row
          float ov = v;
          if (tok < 2048) {
            float pos = jlow ? (float)(tok & 63) : (float)(tok >> 6);
            float s, c;
            __sincosf(pos * freq, &s, &c);
            ov = ((col & 1) == 0) ? (v * c - p * s) : (p * s + v * c);
          }
          if (z == 0) ov *= SC;  // fold softmax scale*log2e into Q
          ((z == 0) ? Qh : Kh)[row * 1024 + col] = f2bf(ov);
        } else {
          int bb = row >= NK ? 1 : 0;
          int tok = row - bb * NK;
          int h = col >> 6, dd = col & 63;
          Vt[((bb * NH + h) * HD + dd) * NK + tok] = f2bf(v);
        }
      }
    }
  }
}

// ---------- O projection: f32 out ----------
__global__ __launch_bounds__(256, 2) void gemm_o(const u16* __restrict__ A,
                                                 const u16* __restrict__ Bt,
                                                 const float* __restrict__ bias,
                                                 float* __restrict__ Cout) {
  __shared__ u16 As[128 * 32];
  __shared__ u16 Bs[128 * 32];
  const int t = threadIdx.x;
  const int lane = t & 63, w = t >> 6;
  const int lc = lane & 15, lq = lane >> 4;
  const int m0 = blockIdx.y * 128, n0 = blockIdx.x * 128;
  const int wm = (w >> 1) * 64, wn = (w & 1) * 64;
  f32x4 acc[4][4] = {};
  const u16* ga = A + (m0 + (t >> 2)) * 1024 + (t & 3) * 8;
  const u16* gb = Bt + (n0 + (t >> 2)) * 1024 + (t & 3) * 8;
  char* lA = (char*)As + w * 1024;
  char* lB = (char*)Bs + w * 1024;
  for (int k0 = 0; k0 < 1024; k0 += 32) {
    if (k0) __syncthreads();
    GLL16(ga + k0, lA);
    GLL16(ga + 64 * 1024 + k0, lA + 4096);
    GLL16(gb + k0, lB);
    GLL16(gb + 64 * 1024 + k0, lB + 4096);
    __syncthreads();
    bf16x8 af[4], bf[4];
#pragma unroll
    for (int i = 0; i < 4; ++i) {
      af[i] = *(const bf16x8*)&As[(wm + i * 16 + lc) * 32 + lq * 8];
      bf[i] = *(const bf16x8*)&Bs[(wn + i * 16 + lc) * 32 + lq * 8];
    }
#pragma unroll
    for (int mi = 0; mi < 4; ++mi)
#pragma unroll
      for (int ni = 0; ni < 4; ++ni)
        acc[mi][ni] = __builtin_amdgcn_mfma_f32_16x16x32_bf16(af[mi], bf[ni], acc[mi][ni], 0, 0, 0);
  }
#pragma unroll
  for (int mi = 0; mi < 4; ++mi)
#pragma unroll
    for (int ni = 0; ni < 4; ++ni) {
      int col = n0 + wn + ni * 16 + lc;
      float bv = bias[col];
#pragma unroll
      for (int r = 0; r < 4; ++r) {
        int row = m0 + wm + mi * 16 + lq * 4 + r;
        Cout[row * 1024 + col] = acc[mi][ni][r] + bv;
      }
    }
}

// ---------- flash attention, no-max softmax (p = exp2(s), l via ones-MFMA) ----
// Scores are bounded (|q.k|*SC < ~12) so fixed max=0 is numerically safe; P/l is
// mathematically identical to max-subtracted softmax. No shuffles, no rescale.
#define LSTR 72
__global__ __launch_bounds__(256, 2) void attn_kernel(const u16* __restrict__ Qh,
                                                      const u16* __restrict__ Kh,
                                                      const u16* __restrict__ Vt,
                                                      u16* __restrict__ AO) {
  __shared__ u16 QPs[128 * LSTR];  // Q staging, then P round-trip (wave-private rows)
  __shared__ u16 Ks[64 * LSTR];
  __shared__ u16 Vs[64 * LSTR];  // transposed: [dd][key]
  const int t = threadIdx.x;
  const int lane = t & 63, w = t >> 6;
  const int lc = lane & 15, lq = lane >> 4;
  const int rr = lane >> 3, s = lane & 7;
  const int qt = blockIdx.x, h = blockIdx.y, b = blockIdx.z;

  // ---- stage Q into wave-private LDS rows (no barrier needed) ----
  {
    const u16* gq = Qh + (b * NQ + qt * 128 + w * 32 + rr) * CD + h * HD + s * 8;
    u16* lqp = &QPs[(w * 32 + rr) * LSTR + s * 8];
#pragma unroll
    for (int i = 0; i < 4; ++i)
      *(uint4*)(lqp + i * 8 * LSTR) = *(const uint4*)(gq + i * 8 * CD);
  }
  bf16x8 qf[2][2];
#pragma unroll
  for (int mi = 0; mi < 2; ++mi)
#pragma unroll
    for (int kk = 0; kk < 2; ++kk)
      qf[mi][kk] = *(const bf16x8*)&QPs[(w * 32 + mi * 16 + lc) * LSTR + kk * 32 + lq * 8];

  // ones B-fragment for row-sum MFMA
  bf16x8 ones;
  {
    u32* op = (u32*)&ones;
    op[0] = op[1] = op[2] = op[3] = 0x3F803F80u;  // bf16 1.0 pairs
  }

  // ---- K/V pipeline registers ----
  const u16* gK = Kh + (b * NK + w * 16 + rr) * CD + h * HD + s * 8;
  const u16* gV = Vt + ((b * NH + h) * HD + w * 16 + rr) * NK + s * 8;
  uint4 kreg0, kreg1, vreg0, vreg1;
  kreg0 = *(const uint4*)(gK);
  kreg1 = *(const uint4*)(gK + 8 * CD);
  vreg0 = *(const uint4*)(gV);
  vreg1 = *(const uint4*)(gV + 8 * NK);

  f32x4 oacc[2][4] = {};
  f32x4 lacc[2] = {};

  for (int j0 = 0; j0 < NK; j0 += 64) {
    __syncthreads();  // everyone done reading previous Ks/Vs
    *(uint4*)&Ks[(w * 16 + rr) * LSTR + s * 8] = kreg0;
    *(uint4*)&Ks[(w * 16 + 8 + rr) * LSTR + s * 8] = kreg1;
    *(uint4*)&Vs[(w * 16 + rr) * LSTR + s * 8] = vreg0;
    *(uint4*)&Vs[(w * 16 + 8 + rr) * LSTR + s * 8] = vreg1;
    __syncthreads();
    if (j0 + 64 < NK) {  // prefetch next tile, in flight during compute
      kreg0 = *(const uint4*)(gK + (j0 + 64) * CD);
      kreg1 = *(const uint4*)(gK + (j0 + 64) * CD + 8 * CD);
      vreg0 = *(const uint4*)(gV + j0 + 64);
      vreg1 = *(const uint4*)(gV + 8 * NK + j0 + 64);
    }

    f32x4 sacc[2][4] = {};
#pragma unroll
    for (int ni = 0; ni < 4; ++ni) {
      bf16x8 k0f = *(const bf16x8*)&Ks[(ni * 16 + lc) * LSTR + lq * 8];
      bf16x8 k1f = *(const bf16x8*)&Ks[(ni * 16 + lc) * LSTR + 32 + lq * 8];
#pragma unroll
      for (int mi = 0; mi < 2; ++mi) {
        sacc[mi][ni] = __builtin_amdgcn_mfma_f32_16x16x32_bf16(qf[mi][0], k0f, sacc[mi][ni], 0, 0, 0);
        sacc[mi][ni] = __builtin_amdgcn_mfma_f32_16x16x32_bf16(qf[mi][1], k1f, sacc[mi][ni], 0, 0, 0);
      }
    }
    // p = exp2(s)  (Q pre-scaled by SC); straight to LDS in A-layout
#pragma unroll
    for (int mi = 0; mi < 2; ++mi)
#pragma unroll
      for (int ni = 0; ni < 4; ++ni)
#pragma unroll
        for (int r = 0; r < 4; ++r)
          QPs[(w * 32 + mi * 16 + lq * 4 + r) * LSTR + ni * 16 + lc] =
              f2bf_pos(__builtin_amdgcn_exp2f(sacc[mi][ni][r]));
#pragma unroll
    for (int kc = 0; kc < 2; ++kc) {
      bf16x8 pf[2], vf[4];
#pragma unroll
      for (int mi = 0; mi < 2; ++mi)
        pf[mi] = *(const bf16x8*)&QPs[(w * 32 + mi * 16 + lc) * LSTR + kc * 32 + lq * 8];
#pragma unroll
      for (int di = 0; di < 4; ++di)
        vf[di] = *(const bf16x8*)&Vs[(di * 16 + lc) * LSTR + kc * 32 + lq * 8];
#pragma unroll
      for (int mi = 0; mi < 2; ++mi) {
#pragma unroll
        for (int di = 0; di < 4; ++di)
          oacc[mi][di] = __builtin_amdgcn_mfma_f32_16x16x32_bf16(pf[mi], vf[di], oacc[mi][di], 0, 0, 0);
        lacc[mi] = __builtin_amdgcn_mfma_f32_16x16x32_bf16(pf[mi], ones, lacc[mi], 0, 0, 0);
      }
    }
  }
#pragma unroll
  for (int mi = 0; mi < 2; ++mi)
#pragma unroll
    for (int r = 0; r < 4; ++r) {
      float inv = 1.0f / lacc[mi][r];
#pragma unroll
      for (int di = 0; di < 4; ++di) {
        int row = qt * 128 + w * 32 + mi * 16 + lq * 4 + r;
        int col = h * HD + di * 16 + lc;
        AO[(b * NQ + row) * CD + col] = f2bf(oacc[mi][di][r] * inv);
      }
    }
}

extern "C" void kernel_launch(void* const* d_in, const int* in_sizes, int n_in,
                              void* d_out, int out_size, void* d_ws, size_t ws_size,
                              hipStream_t stream) {
  const float* q  = (const float*)d_in[0];
  const float* k  = (const float*)d_in[1];
  const float* v  = (const float*)d_in[2];
  const float* Wq = (const float*)d_in[3];
  const float* bq = (const float*)d_in[4];
  const float* Wk = (const float*)d_in[5];
  const float* bk = (const float*)d_in[6];
  const float* Wv = (const float*)d_in[7];
  const float* bv = (const float*)d_in[8];
  const float* Wo = (const float*)d_in[9];
  const float* bo = (const float*)d_in[10];

  char* ws = (char*)d_ws;
  size_t off = 0;
  auto alloc = [&](size_t bytes) {
    char* p = ws + off;
    off += (bytes + 255) & ~(size_t)255;
    return p;
  };
  u16* qb  = (u16*)alloc((size_t)B_ * NQ * CD * 2);
  u16* kb  = (u16*)alloc((size_t)B_ * NK * CD * 2);
  u16* vb  = (u16*)alloc((size_t)B_ * NK * CD * 2);
  u16* wqt = (u16*)alloc((size_t)CD * CD * 2);
  u16* wkt = (u16*)alloc((size_t)CD * CD * 2);
  u16* wvt = (u16*)alloc((size_t)CD * CD * 2);
  u16* wot = (u16*)alloc((size_t)CD * CD * 2);
  u16* Qh  = (u16*)alloc((size_t)B_ * NQ * CD * 2);
  u16* Kh  = (u16*)alloc((size_t)B_ * NK * CD * 2);
  u16* Vt  = (u16*)alloc((size_t)B_ * NK * CD * 2);
  u16* AO  = (u16*)alloc((size_t)B_ * NQ * CD * 2);

  cvt3_kernel<<<dim3(4224, 3), 256, 0, stream>>>(q, k, v, qb, kb, vb);
  wtrans_kernel<<<dim3(32, 32, 4), 256, 0, stream>>>(Wq, Wk, Wv, Wo, wqt, wkt, wvt, wot);
  gemm_qkv<<<dim3(8, 33, 3), 256, 0, stream>>>(qb, kb, vb, wqt, wkt, wvt, bq, bk, bv, Qh, Kh, Vt);
  attn_kernel<<<dim3(16, NH, B_), 256, 0, stream>>>(Qh, Kh, Vt, AO);
  gemm_o<<<dim3(8, 32), 256, 0, stream>>>(AO, wot, bo, (float*)d_out);
}

// Round 4
// 262.855 us; speedup vs baseline: 1.5978x; 1.0139x over previous
//
#include <hip/hip_runtime.h>

#define B_ 2
#define NQ 2048
#define NK 2112
#define CD 1024
#define NH 16
#define HD 64

typedef unsigned short u16;
typedef unsigned int u32;
typedef __attribute__((ext_vector_type(8))) __bf16 bf16x8;
typedef __attribute__((ext_vector_type(4))) float f32x4;

#define GPTR(p) ((const __attribute__((address_space(1))) void*)(p))
#define LPTR(p) ((__attribute__((address_space(3))) void*)(p))
#define GLL16(g, l) __builtin_amdgcn_global_load_lds(GPTR(g), LPTR(l), 16, 0, 0)

__device__ __forceinline__ u16 f2bf(float f) {
  u32 u = __float_as_uint(f);
  u32 r = u + 0x7fffu + ((u >> 16) & 1u);
  return (u16)(r >> 16);
}
__device__ __forceinline__ float bf2f(u16 h) { return __uint_as_float(((u32)h) << 16); }

// ---------- f32 -> bf16 convert, all three inputs in one dispatch ----------
__global__ void cvt3_kernel(const float* __restrict__ q, const float* __restrict__ k,
                            const float* __restrict__ v, u16* __restrict__ qb,
                            u16* __restrict__ kb, u16* __restrict__ vb) {
  int z = blockIdx.y;
  const float* src = (z == 0) ? q : (z == 1) ? k : v;
  u16* dst = (z == 0) ? qb : (z == 1) ? kb : vb;
  int n4 = (z == 0) ? (B_ * NQ * CD / 4) : (B_ * NK * CD / 4);
  int i = blockIdx.x * 256 + threadIdx.x;
  if (i >= n4) return;
  float4 vv = ((const float4*)src)[i];
  ushort4 o;
  o.x = f2bf(vv.x); o.y = f2bf(vv.y); o.z = f2bf(vv.z); o.w = f2bf(vv.w);
  ((ushort4*)dst)[i] = o;
}

// ---------- W (1024x1024 f32) -> Wt bf16 with Wt[n][k] = W[k][n] ----------
__global__ void wtrans_kernel(const float* __restrict__ W0, const float* __restrict__ W1,
                              const float* __restrict__ W2, const float* __restrict__ W3,
                              u16* __restrict__ T0, u16* __restrict__ T1,
                              u16* __restrict__ T2, u16* __restrict__ T3) {
  const float* src; u16* dst;
  switch (blockIdx.z) {
    case 0: src = W0; dst = T0; break;
    case 1: src = W1; dst = T1; break;
    case 2: src = W2; dst = T2; break;
    default: src = W3; dst = T3; break;
  }
  __shared__ u16 tile[32][33];
  int t = threadIdx.x;
  int r0 = blockIdx.y * 32, c0 = blockIdx.x * 32;
  int row = t >> 3, c4 = (t & 7) * 4;
  float4 v = *(const float4*)&src[(r0 + row) * 1024 + c0 + c4];
  tile[row][c4 + 0] = f2bf(v.x);
  tile[row][c4 + 1] = f2bf(v.y);
  tile[row][c4 + 2] = f2bf(v.z);
  tile[row][c4 + 3] = f2bf(v.w);
  __syncthreads();
  ushort4 o;
  o.x = tile[c4 + 0][row];
  o.y = tile[c4 + 1][row];
  o.z = tile[c4 + 2][row];
  o.w = tile[c4 + 3][row];
  *(ushort4*)&dst[(c0 + row) * 1024 + r0 + c4] = o;
}

// (1/sqrt(64)) * log2(e) — folded into the Q projection output
#define SC 0.18033688011112042f

// ---------- fused QKV projection GEMM + RoPE epilogue ----------
// z=0: Q (rope, *SC, row-major out), z=1: K (rope tok<2048, row-major out),
// z=2: V (no rope, scatter to Vt[(b,h,dd),tok]).
__global__ __launch_bounds__(256, 2) void gemm_qkv(
    const u16* __restrict__ qb, const u16* __restrict__ kb, const u16* __restrict__ vb,
    const u16* __restrict__ wqt, const u16* __restrict__ wkt, const u16* __restrict__ wvt,
    const float* __restrict__ bq, const float* __restrict__ bk, const float* __restrict__ bv,
    u16* __restrict__ Qh, u16* __restrict__ Kh, u16* __restrict__ Vt) {
  const int z = blockIdx.z;
  if (z == 0 && blockIdx.y >= 32) return;  // Q has 4096 rows only
  const u16* A = (z == 0) ? qb : (z == 1) ? kb : vb;
  const u16* Bt = (z == 0) ? wqt : (z == 1) ? wkt : wvt;
  const float* bias = (z == 0) ? bq : (z == 1) ? bk : bv;
  const int batch_rows = (z == 0) ? NQ : NK;

  __shared__ u16 As[128 * 32];
  __shared__ u16 Bs[128 * 32];
  const int t = threadIdx.x;
  const int lane = t & 63, w = t >> 6;
  const int lc = lane & 15, lq = lane >> 4;
  const int m0 = blockIdx.y * 128, n0 = blockIdx.x * 128;
  const int wm = (w >> 1) * 64, wn = (w & 1) * 64;
  f32x4 acc[4][4] = {};
  const u16* ga = A + (m0 + (t >> 2)) * 1024 + (t & 3) * 8;
  const u16* gb = Bt + (n0 + (t >> 2)) * 1024 + (t & 3) * 8;
  char* lA = (char*)As + w * 1024;
  char* lB = (char*)Bs + w * 1024;
  for (int k0 = 0; k0 < 1024; k0 += 32) {
    if (k0) __syncthreads();
    GLL16(ga + k0, lA);
    GLL16(ga + 64 * 1024 + k0, lA + 4096);
    GLL16(gb + k0, lB);
    GLL16(gb + 64 * 1024 + k0, lB + 4096);
    __syncthreads();
    bf16x8 af[4], bf[4];
#pragma unroll
    for (int i = 0; i < 4; ++i) {
      af[i] = *(const bf16x8*)&As[(wm + i * 16 + lc) * 32 + lq * 8];
      bf[i] = *(const bf16x8*)&Bs[(wn + i * 16 + lc) * 32 + lq * 8];
    }
#pragma unroll
    for (int mi = 0; mi < 4; ++mi)
#pragma unroll
      for (int ni = 0; ni < 4; ++ni)
        acc[mi][ni] = __builtin_amdgcn_mfma_f32_16x16x32_bf16(af[mi], bf[ni], acc[mi][ni], 0, 0, 0);
  }
#pragma unroll
  for (int mi = 0; mi < 4; ++mi) {
#pragma unroll
    for (int ni = 0; ni < 4; ++ni) {
      int col = n0 + wn + ni * 16 + lc;
      float bv_ = bias[col];
      int j = (col >> 1) & 31;  // pair index within head
      bool jlow = j < 16;
      float freq = exp2f((float)(jlow ? j : j - 16) * -0.8304820237f);
#pragma unroll
      for (int r = 0; r < 4; ++r) {
        int row = m0 + wm + mi * 16 + lq * 4 + r;
        float v = acc[mi][ni][r] + bv_;
        if (z < 2) {
          int bb = row >= batch_rows ? 1 : 0;
          int tok = row - bb * batch_rows;
          float p = __shfl_xor(v, 1, 64);  // rope partner (col^1), same row
          float ov = v;
          if (tok < 2048) {
            float pos = jlow ? (float)(tok & 63) : (float)(tok >> 6);
            float s, c;
            __sincosf(pos * freq, &s, &c);
            ov = ((col & 1) == 0) ? (v * c - p * s) : (p * s + v * c);
          }
          if (z == 0) ov *= SC;  // fold softmax scale*log2e into Q
          ((z == 0) ? Qh : Kh)[row * 1024 + col] = f2bf(ov);
        } else {
          int bb = row >= NK ? 1 : 0;
          int tok = row - bb * NK;
          int h = col >> 6, dd = col & 63;
          Vt[((bb * NH + h) * HD + dd) * NK + tok] = f2bf(v);
        }
      }
    }
  }
}

// ---------- O projection: f32 out ----------
__global__ __launch_bounds__(256, 2) void gemm_o(const u16* __restrict__ A,
                                                 const u16* __restrict__ Bt,
                                                 const float* __restrict__ bias,
                                                 float* __restrict__ Cout) {
  __shared__ u16 As[128 * 32];
  __shared__ u16 Bs[128 * 32];
  const int t = threadIdx.x;
  const int lane = t & 63, w = t >> 6;
  const int lc = lane & 15, lq = lane >> 4;
  const int m0 = blockIdx.y * 128, n0 = blockIdx.x * 128;
  const int wm = (w >> 1) * 64, wn = (w & 1) * 64;
  f32x4 acc[4][4] = {};
  const u16* ga = A + (m0 + (t >> 2)) * 1024 + (t & 3) * 8;
  const u16* gb = Bt + (n0 + (t >> 2)) * 1024 + (t & 3) * 8;
  char* lA = (char*)As + w * 1024;
  char* lB = (char*)Bs + w * 1024;
  for (int k0 = 0; k0 < 1024; k0 += 32) {
    if (k0) __syncthreads();
    GLL16(ga + k0, lA);
    GLL16(ga + 64 * 1024 + k0, lA + 4096);
    GLL16(gb + k0, lB);
    GLL16(gb + 64 * 1024 + k0, lB + 4096);
    __syncthreads();
    bf16x8 af[4], bf[4];
#pragma unroll
    for (int i = 0; i < 4; ++i) {
      af[i] = *(const bf16x8*)&As[(wm + i * 16 + lc) * 32 + lq * 8];
      bf[i] = *(const bf16x8*)&Bs[(wn + i * 16 + lc) * 32 + lq * 8];
    }
#pragma unroll
    for (int mi = 0; mi < 4; ++mi)
#pragma unroll
      for (int ni = 0; ni < 4; ++ni)
        acc[mi][ni] = __builtin_amdgcn_mfma_f32_16x16x32_bf16(af[mi], bf[ni], acc[mi][ni], 0, 0, 0);
  }
#pragma unroll
  for (int mi = 0; mi < 4; ++mi)
#pragma unroll
    for (int ni = 0; ni < 4; ++ni) {
      int col = n0 + wn + ni * 16 + lc;
      float bv = bias[col];
#pragma unroll
      for (int r = 0; r < 4; ++r) {
        int row = m0 + wm + mi * 16 + lq * 4 + r;
        Cout[row * 1024 + col] = acc[mi][ni][r] + bv;
      }
    }
}

// ---------- flash attention, no-max softmax, S^T layout for packed P-writes ----
// QK^T computed operand-swapped (S^T = K.Q^T): C-layout gives each lane 4
// consecutive KEYS of one q-row -> exp2 + pack -> single ds_write_b64 per tile
// (replaces 32 scalar ds_write_b16 = half the LDS-pipe cost of the old loop).
#define LSTR 72
__global__ __launch_bounds__(256, 2) void attn_kernel(const u16* __restrict__ Qh,
                                                      const u16* __restrict__ Kh,
                                                      const u16* __restrict__ Vt,
                                                      u16* __restrict__ AO) {
  __shared__ u16 QPs[128 * LSTR];  // Q staging, then P[q][key] (wave-private rows)
  __shared__ u16 Ks[64 * LSTR];
  __shared__ u16 Vs[64 * LSTR];  // transposed: [dd][key]
  const int t = threadIdx.x;
  const int lane = t & 63, w = t >> 6;
  const int lc = lane & 15, lq = lane >> 4;
  const int rr = lane >> 3, s = lane & 7;
  const int qt = blockIdx.x, h = blockIdx.y, b = blockIdx.z;

  // ---- stage Q into wave-private LDS rows (no barrier needed) ----
  {
    const u16* gq = Qh + (b * NQ + qt * 128 + w * 32 + rr) * CD + h * HD + s * 8;
    u16* lqp = &QPs[(w * 32 + rr) * LSTR + s * 8];
#pragma unroll
    for (int i = 0; i < 4; ++i)
      *(uint4*)(lqp + i * 8 * LSTR) = *(const uint4*)(gq + i * 8 * CD);
  }
  bf16x8 qf[2][2];  // [ni(q-16-block)][kk] — B-fragment of Q^T == A-layout read
#pragma unroll
  for (int ni = 0; ni < 2; ++ni)
#pragma unroll
    for (int kk = 0; kk < 2; ++kk)
      qf[ni][kk] = *(const bf16x8*)&QPs[(w * 32 + ni * 16 + lc) * LSTR + kk * 32 + lq * 8];

  // ones B-fragment for row-sum MFMA
  bf16x8 ones;
  {
    u32* op = (u32*)&ones;
    op[0] = op[1] = op[2] = op[3] = 0x3F803F80u;  // bf16 1.0 pairs
  }

  // ---- K/V pipeline registers ----
  const u16* gK = Kh + (b * NK + w * 16 + rr) * CD + h * HD + s * 8;
  const u16* gV = Vt + ((b * NH + h) * HD + w * 16 + rr) * NK + s * 8;
  uint4 kreg0, kreg1, vreg0, vreg1;
  kreg0 = *(const uint4*)(gK);
  kreg1 = *(const uint4*)(gK + 8 * CD);
  vreg0 = *(const uint4*)(gV);
  vreg1 = *(const uint4*)(gV + 8 * NK);

  f32x4 oacc[2][4] = {};
  f32x4 lacc[2] = {};

  for (int j0 = 0; j0 < NK; j0 += 64) {
    __syncthreads();  // everyone done reading previous Ks/Vs
    *(uint4*)&Ks[(w * 16 + rr) * LSTR + s * 8] = kreg0;
    *(uint4*)&Ks[(w * 16 + 8 + rr) * LSTR + s * 8] = kreg1;
    *(uint4*)&Vs[(w * 16 + rr) * LSTR + s * 8] = vreg0;
    *(uint4*)&Vs[(w * 16 + 8 + rr) * LSTR + s * 8] = vreg1;
    __syncthreads();
    if (j0 + 64 < NK) {  // prefetch next tile, in flight during compute
      kreg0 = *(const uint4*)(gK + (j0 + 64) * CD);
      kreg1 = *(const uint4*)(gK + (j0 + 64) * CD + 8 * CD);
      vreg0 = *(const uint4*)(gV + j0 + 64);
      vreg1 = *(const uint4*)(gV + 8 * NK + j0 + 64);
    }

    // S^T = K . Q^T : st[ni][mi], m = key (mi*16 + lq*4 + r), n = q (ni*16 + lc)
    f32x4 st[2][4] = {};
#pragma unroll
    for (int mi = 0; mi < 4; ++mi) {
      bf16x8 k0f = *(const bf16x8*)&Ks[(mi * 16 + lc) * LSTR + lq * 8];
      bf16x8 k1f = *(const bf16x8*)&Ks[(mi * 16 + lc) * LSTR + 32 + lq * 8];
#pragma unroll
      for (int ni = 0; ni < 2; ++ni) {
        st[ni][mi] = __builtin_amdgcn_mfma_f32_16x16x32_bf16(k0f, qf[ni][0], st[ni][mi], 0, 0, 0);
        st[ni][mi] = __builtin_amdgcn_mfma_f32_16x16x32_bf16(k1f, qf[ni][1], st[ni][mi], 0, 0, 0);
      }
    }
    // p = exp2(s); 4 consecutive keys per lane -> pack -> one b64 write each
#pragma unroll
    for (int ni = 0; ni < 2; ++ni)
#pragma unroll
      for (int mi = 0; mi < 4; ++mi) {
        u32 e0 = __float_as_uint(__builtin_amdgcn_exp2f(st[ni][mi][0])) + 0x8000u;
        u32 e1 = __float_as_uint(__builtin_amdgcn_exp2f(st[ni][mi][1])) + 0x8000u;
        u32 e2 = __float_as_uint(__builtin_amdgcn_exp2f(st[ni][mi][2])) + 0x8000u;
        u32 e3 = __float_as_uint(__builtin_amdgcn_exp2f(st[ni][mi][3])) + 0x8000u;
        uint2 pk;
        pk.x = __builtin_amdgcn_perm(e1, e0, 0x07060302u);  // bf(e0) | bf(e1)<<16
        pk.y = __builtin_amdgcn_perm(e3, e2, 0x07060302u);
        *(uint2*)&QPs[(w * 32 + ni * 16 + lc) * LSTR + mi * 16 + lq * 4] = pk;
      }
    // O += P.V ; l += P.1  (P read back in A-layout: contiguous b128)
#pragma unroll
    for (int kc = 0; kc < 2; ++kc) {
      bf16x8 pf[2], vf[4];
#pragma unroll
      for (int ni = 0; ni < 2; ++ni)
        pf[ni] = *(const bf16x8*)&QPs[(w * 32 + ni * 16 + lc) * LSTR + kc * 32 + lq * 8];
#pragma unroll
      for (int di = 0; di < 4; ++di)
        vf[di] = *(const bf16x8*)&Vs[(di * 16 + lc) * LSTR + kc * 32 + lq * 8];
#pragma unroll
      for (int ni = 0; ni < 2; ++ni) {
#pragma unroll
        for (int di = 0; di < 4; ++di)
          oacc[ni][di] = __builtin_amdgcn_mfma_f32_16x16x32_bf16(pf[ni], vf[di], oacc[ni][di], 0, 0, 0);
        lacc[ni] = __builtin_amdgcn_mfma_f32_16x16x32_bf16(pf[ni], ones, lacc[ni], 0, 0, 0);
      }
    }
  }
#pragma unroll
  for (int ni = 0; ni < 2; ++ni)
#pragma unroll
    for (int r = 0; r < 4; ++r) {
      float inv = 1.0f / lacc[ni][r];
#pragma unroll
      for (int di = 0; di < 4; ++di) {
        int row = qt * 128 + w * 32 + ni * 16 + lq * 4 + r;
        int col = h * HD + di * 16 + lc;
        AO[(b * NQ + row) * CD + col] = f2bf(oacc[ni][di][r] * inv);
      }
    }
}

extern "C" void kernel_launch(void* const* d_in, const int* in_sizes, int n_in,
                              void* d_out, int out_size, void* d_ws, size_t ws_size,
                              hipStream_t stream) {
  const float* q  = (const float*)d_in[0];
  const float* k  = (const float*)d_in[1];
  const float* v  = (const float*)d_in[2];
  const float* Wq = (const float*)d_in[3];
  const float* bq = (const float*)d_in[4];
  const float* Wk = (const float*)d_in[5];
  const float* bk = (const float*)d_in[6];
  const float* Wv = (const float*)d_in[7];
  const float* bv = (const float*)d_in[8];
  const float* Wo = (const float*)d_in[9];
  const float* bo = (const float*)d_in[10];

  char* ws = (char*)d_ws;
  size_t off = 0;
  auto alloc = [&](size_t bytes) {
    char* p = ws + off;
    off += (bytes + 255) & ~(size_t)255;
    return p;
  };
  u16* qb  = (u16*)alloc((size_t)B_ * NQ * CD * 2);
  u16* kb  = (u16*)alloc((size_t)B_ * NK * CD * 2);
  u16* vb  = (u16*)alloc((size_t)B_ * NK * CD * 2);
  u16* wqt = (u16*)alloc((size_t)CD * CD * 2);
  u16* wkt = (u16*)alloc((size_t)CD * CD * 2);
  u16* wvt = (u16*)alloc((size_t)CD * CD * 2);
  u16* wot = (u16*)alloc((size_t)CD * CD * 2);
  u16* Qh  = (u16*)alloc((size_t)B_ * NQ * CD * 2);
  u16* Kh  = (u16*)alloc((size_t)B_ * NK * CD * 2);
  u16* Vt  = (u16*)alloc((size_t)B_ * NK * CD * 2);
  u16* AO  = (u16*)alloc((size_t)B_ * NQ * CD * 2);

  cvt3_kernel<<<dim3(4224, 3), 256, 0, stream>>>(q, k, v, qb, kb, vb);
  wtrans_kernel<<<dim3(32, 32, 4), 256, 0, stream>>>(Wq, Wk, Wv, Wo, wqt, wkt, wvt, wot);
  gemm_qkv<<<dim3(8, 33, 3), 256, 0, stream>>>(qb, kb, vb, wqt, wkt, wvt, bq, bk, bv, Qh, Kh, Vt);
  attn_kernel<<<dim3(16, NH, B_), 256, 0, stream>>>(Qh, Kh, Vt, AO);
  gemm_o<<<dim3(8, 32), 256, 0, stream>>>(AO, wot, bo, (float*)d_out);
}

// Round 5
// 261.273 us; speedup vs baseline: 1.6074x; 1.0061x over previous
//
#include <hip/hip_runtime.h>

#define B_ 2
#define NQ 2048
#define NK 2112
#define CD 1024
#define NH 16
#define HD 64

typedef unsigned short u16;
typedef unsigned int u32;
typedef __attribute__((ext_vector_type(8))) __bf16 bf16x8;
typedef __attribute__((ext_vector_type(4))) float f32x4;

#define GPTR(p) ((const __attribute__((address_space(1))) void*)(p))
#define LPTR(p) ((__attribute__((address_space(3))) void*)(p))
#define GLL16(g, l) __builtin_amdgcn_global_load_lds(GPTR(g), LPTR(l), 16, 0, 0)

__device__ __forceinline__ u16 f2bf(float f) {
  u32 u = __float_as_uint(f);
  u32 r = u + 0x7fffu + ((u >> 16) & 1u);
  return (u16)(r >> 16);
}
__device__ __forceinline__ float bf2f(u16 h) { return __uint_as_float(((u32)h) << 16); }

// (1/sqrt(64)) * log2(e) — folded into the Q projection output
#define SC 0.18033688011112042f
// -log2(theta)/16 and theta^(-1/16)
#define NEGL2T 0.8304820237f
#define FSTEP 0.5623413252f

// ---------- prep: f32->bf16 convert (y=0..2) + weight transpose (y=3) ----------
__global__ void prep_kernel(const float* __restrict__ q, const float* __restrict__ k,
                            const float* __restrict__ v, u16* __restrict__ qb,
                            u16* __restrict__ kb, u16* __restrict__ vb,
                            const float* __restrict__ W0, const float* __restrict__ W1,
                            const float* __restrict__ W2, const float* __restrict__ W3,
                            u16* __restrict__ T0, u16* __restrict__ T1,
                            u16* __restrict__ T2, u16* __restrict__ T3) {
  __shared__ u16 tile[32][33];
  int y = blockIdx.y;
  int t = threadIdx.x;
  if (y < 3) {
    const float* src = (y == 0) ? q : (y == 1) ? k : v;
    u16* dst = (y == 0) ? qb : (y == 1) ? kb : vb;
    int n4 = (y == 0) ? (B_ * NQ * CD / 4) : (B_ * NK * CD / 4);
    int i = blockIdx.x * 256 + t;
    if (i >= n4) return;
    float4 vv = ((const float4*)src)[i];
    ushort4 o;
    o.x = f2bf(vv.x); o.y = f2bf(vv.y); o.z = f2bf(vv.z); o.w = f2bf(vv.w);
    ((ushort4*)dst)[i] = o;
  } else {
    int x = blockIdx.x;
    if (x >= 4096) return;
    int which = x >> 10, xy = x & 1023;
    const float* src = (which == 0) ? W0 : (which == 1) ? W1 : (which == 2) ? W2 : W3;
    u16* dst = (which == 0) ? T0 : (which == 1) ? T1 : (which == 2) ? T2 : T3;
    int r0 = (xy >> 5) * 32, c0 = (xy & 31) * 32;
    int row = t >> 3, c4 = (t & 7) * 4;
    float4 vv = *(const float4*)&src[(r0 + row) * 1024 + c0 + c4];
    tile[row][c4 + 0] = f2bf(vv.x);
    tile[row][c4 + 1] = f2bf(vv.y);
    tile[row][c4 + 2] = f2bf(vv.z);
    tile[row][c4 + 3] = f2bf(vv.w);
    __syncthreads();
    ushort4 o;
    o.x = tile[c4 + 0][row];
    o.y = tile[c4 + 1][row];
    o.z = tile[c4 + 2][row];
    o.w = tile[c4 + 3][row];
    *(ushort4*)&dst[(c0 + row) * 1024 + r0 + c4] = o;
  }
}

// ---------- fused QKV projection GEMM + RoPE epilogue ----------
// 128x128 tile, BK=32. z=0: Q (swapped MFMA -> C^T layout, in-lane rope, *SC),
// z=1: K (same, rope only tok<2048), z=2: V (normal order, packed tok-contiguous
// scatter into Vt[(b,h,dd),tok]).
__global__ __launch_bounds__(256, 2) void gemm_qkv(
    const u16* __restrict__ qb, const u16* __restrict__ kb, const u16* __restrict__ vb,
    const u16* __restrict__ wqt, const u16* __restrict__ wkt, const u16* __restrict__ wvt,
    const float* __restrict__ bq, const float* __restrict__ bk, const float* __restrict__ bv,
    u16* __restrict__ Qh, u16* __restrict__ Kh, u16* __restrict__ Vt) {
  __shared__ u16 As[128 * 32];
  __shared__ u16 Bs[128 * 32];
  const int z = blockIdx.z;
  if (z == 0 && blockIdx.y >= 32) return;  // Q has 4096 rows only
  const u16* A = (z == 0) ? qb : (z == 1) ? kb : vb;
  const u16* Bt = (z == 0) ? wqt : (z == 1) ? wkt : wvt;
  const float* bias = (z == 0) ? bq : (z == 1) ? bk : bv;
  const int BR = (z == 0) ? NQ : NK;  // rows per batch

  const int t = threadIdx.x;
  const int lane = t & 63, w = t >> 6;
  const int lc = lane & 15, lq = lane >> 4;
  const int m0 = blockIdx.y * 128, n0 = blockIdx.x * 128;
  const int wm = (w >> 1) * 64, wn = (w & 1) * 64;
  f32x4 acc[4][4] = {};
  const u16* ga = A + (m0 + (t >> 2)) * 1024 + (t & 3) * 8;
  const u16* gb = Bt + (n0 + (t >> 2)) * 1024 + (t & 3) * 8;
  char* lA = (char*)As + w * 1024;
  char* lB = (char*)Bs + w * 1024;
  const bool swap = (z < 2);
  for (int k0 = 0; k0 < 1024; k0 += 32) {
    if (k0) __syncthreads();
    GLL16(ga + k0, lA);
    GLL16(ga + 64 * 1024 + k0, lA + 4096);
    GLL16(gb + k0, lB);
    GLL16(gb + 64 * 1024 + k0, lB + 4096);
    __syncthreads();
    bf16x8 af[4], bf[4];
#pragma unroll
    for (int i = 0; i < 4; ++i) {
      af[i] = *(const bf16x8*)&As[(wm + i * 16 + lc) * 32 + lq * 8];
      bf[i] = *(const bf16x8*)&Bs[(wn + i * 16 + lc) * 32 + lq * 8];
    }
    if (swap) {
      // acc[mi][ni] = (W row ni-block) x (A row mi-block): C^T layout
#pragma unroll
      for (int mi = 0; mi < 4; ++mi)
#pragma unroll
        for (int ni = 0; ni < 4; ++ni)
          acc[mi][ni] = __builtin_amdgcn_mfma_f32_16x16x32_bf16(bf[ni], af[mi], acc[mi][ni], 0, 0, 0);
    } else {
#pragma unroll
      for (int mi = 0; mi < 4; ++mi)
#pragma unroll
        for (int ni = 0; ni < 4; ++ni)
          acc[mi][ni] = __builtin_amdgcn_mfma_f32_16x16x32_bf16(af[mi], bf[ni], acc[mi][ni], 0, 0, 0);
    }
  }

  if (swap) {
    // C^T layout: lane holds row = m0+wm+mi*16+lc, cols cb..cb+3 (in-lane rope pairs)
    u16* Out = (z == 0) ? Qh : Kh;
    const bool isQ = (z == 0);
#pragma unroll
    for (int ni = 0; ni < 4; ++ni) {
      int cb = n0 + wn + ni * 16 + lq * 4;
      float4 bv4 = *(const float4*)&bias[cb];
      int jj = (ni * 8 + lq * 2) & 15;  // pair idx mod 16 (ni<2: x-freqs, ni>=2: y-freqs)
      bool jl = ni < 2;
      float f0 = exp2f((float)jj * -NEGL2T);
      float f1 = f0 * FSTEP;
#pragma unroll
      for (int mi = 0; mi < 4; ++mi) {
        int row = m0 + wm + mi * 16 + lc;
        int bb = row >= BR ? 1 : 0;
        int tok = row - bb * BR;
        float v0 = acc[mi][ni][0] + bv4.x;
        float v1 = acc[mi][ni][1] + bv4.y;
        float v2 = acc[mi][ni][2] + bv4.z;
        float v3 = acc[mi][ni][3] + bv4.w;
        uint2 pk;
        if (isQ || tok < 2048) {
          float pos = jl ? (float)(tok & 63) : (float)(tok >> 6);
          float s0, c0, s1, c1;
          __sincosf(pos * f0, &s0, &c0);
          __sincosf(pos * f1, &s1, &c1);
          float o0 = v0 * c0 - v1 * s0, o1 = v0 * s0 + v1 * c0;
          float o2 = v2 * c1 - v3 * s1, o3 = v2 * s1 + v3 * c1;
          if (isQ) { o0 *= SC; o1 *= SC; o2 *= SC; o3 *= SC; }
          pk.x = (u32)f2bf(o0) | ((u32)f2bf(o1) << 16);
          pk.y = (u32)f2bf(o2) | ((u32)f2bf(o3) << 16);
        } else {
          pk.x = (u32)f2bf(v0) | ((u32)f2bf(v1) << 16);
          pk.y = (u32)f2bf(v2) | ((u32)f2bf(v3) << 16);
        }
        *(uint2*)&Out[row * 1024 + cb] = pk;
      }
    }
  } else {
    // V: normal layout: lane holds col, 4 consecutive toks -> one uint2 into Vt
#pragma unroll
    for (int ni = 0; ni < 4; ++ni) {
      int col = n0 + wn + ni * 16 + lc;
      float bv = bias[col];
      int hh = col >> 6, dd = col & 63;
#pragma unroll
      for (int mi = 0; mi < 4; ++mi) {
        int row0 = m0 + wm + mi * 16 + lq * 4;
        int bb = row0 >= NK ? 1 : 0;
        int tok0 = row0 - bb * NK;  // 4-row group never straddles the batch boundary
        float v0 = acc[mi][ni][0] + bv;
        float v1 = acc[mi][ni][1] + bv;
        float v2 = acc[mi][ni][2] + bv;
        float v3 = acc[mi][ni][3] + bv;
        uint2 pk;
        pk.x = (u32)f2bf(v0) | ((u32)f2bf(v1) << 16);
        pk.y = (u32)f2bf(v2) | ((u32)f2bf(v3) << 16);
        *(uint2*)&Vt[((bb * NH + hh) * HD + dd) * NK + tok0] = pk;
      }
    }
  }
}

// ---------- O projection: 128x64 tile (512 blocks = 2/CU), swapped MFMA, f32x4 out --
__global__ __launch_bounds__(256, 2) void gemm_o(const u16* __restrict__ A,
                                                 const u16* __restrict__ Bt,
                                                 const float* __restrict__ bias,
                                                 float* __restrict__ Cout) {
  __shared__ u16 As[128 * 32];
  __shared__ u16 Bs[64 * 32];
  const int t = threadIdx.x;
  const int lane = t & 63, w = t >> 6;
  const int lc = lane & 15, lq = lane >> 4;
  const int m0 = blockIdx.y * 128, n0 = blockIdx.x * 64;
  const int wm = (w >> 1) * 64, wn = (w & 1) * 32;
  f32x4 acc[4][2] = {};
  const u16* ga = A + (m0 + (t >> 2)) * 1024 + (t & 3) * 8;
  const u16* gb = Bt + (n0 + (t >> 2)) * 1024 + (t & 3) * 8;
  char* lA = (char*)As + w * 1024;
  char* lB = (char*)Bs + w * 1024;
  for (int k0 = 0; k0 < 1024; k0 += 32) {
    if (k0) __syncthreads();
    GLL16(ga + k0, lA);
    GLL16(ga + 64 * 1024 + k0, lA + 4096);
    GLL16(gb + k0, lB);  // 64 rows of B^T strip, one round
    __syncthreads();
    bf16x8 af[4], bf[2];
#pragma unroll
    for (int i = 0; i < 4; ++i)
      af[i] = *(const bf16x8*)&As[(wm + i * 16 + lc) * 32 + lq * 8];
#pragma unroll
    for (int i = 0; i < 2; ++i)
      bf[i] = *(const bf16x8*)&Bs[(wn + i * 16 + lc) * 32 + lq * 8];
#pragma unroll
    for (int mi = 0; mi < 4; ++mi)
#pragma unroll
      for (int ni = 0; ni < 2; ++ni)
        acc[mi][ni] = __builtin_amdgcn_mfma_f32_16x16x32_bf16(bf[ni], af[mi], acc[mi][ni], 0, 0, 0);
  }
#pragma unroll
  for (int ni = 0; ni < 2; ++ni) {
    int cb = n0 + wn + ni * 16 + lq * 4;
    float4 bv4 = *(const float4*)&bias[cb];
#pragma unroll
    for (int mi = 0; mi < 4; ++mi) {
      int row = m0 + wm + mi * 16 + lc;
      float4 o;
      o.x = acc[mi][ni][0] + bv4.x;
      o.y = acc[mi][ni][1] + bv4.y;
      o.z = acc[mi][ni][2] + bv4.z;
      o.w = acc[mi][ni][3] + bv4.w;
      *(float4*)&Cout[row * 1024 + cb] = o;
    }
  }
}

// ---------- flash attention (unchanged from round 4) ----------
#define LSTR 72
__global__ __launch_bounds__(256, 2) void attn_kernel(const u16* __restrict__ Qh,
                                                      const u16* __restrict__ Kh,
                                                      const u16* __restrict__ Vt,
                                                      u16* __restrict__ AO) {
  __shared__ u16 QPs[128 * LSTR];  // Q staging, then P[q][key] (wave-private rows)
  __shared__ u16 Ks[64 * LSTR];
  __shared__ u16 Vs[64 * LSTR];  // transposed: [dd][key]
  const int t = threadIdx.x;
  const int lane = t & 63, w = t >> 6;
  const int lc = lane & 15, lq = lane >> 4;
  const int rr = lane >> 3, s = lane & 7;
  const int qt = blockIdx.x, h = blockIdx.y, b = blockIdx.z;

  {
    const u16* gq = Qh + (b * NQ + qt * 128 + w * 32 + rr) * CD + h * HD + s * 8;
    u16* lqp = &QPs[(w * 32 + rr) * LSTR + s * 8];
#pragma unroll
    for (int i = 0; i < 4; ++i)
      *(uint4*)(lqp + i * 8 * LSTR) = *(const uint4*)(gq + i * 8 * CD);
  }
  bf16x8 qf[2][2];
#pragma unroll
  for (int ni = 0; ni < 2; ++ni)
#pragma unroll
    for (int kk = 0; kk < 2; ++kk)
      qf[ni][kk] = *(const bf16x8*)&QPs[(w * 32 + ni * 16 + lc) * LSTR + kk * 32 + lq * 8];

  bf16x8 ones;
  {
    u32* op = (u32*)&ones;
    op[0] = op[1] = op[2] = op[3] = 0x3F803F80u;  // bf16 1.0 pairs
  }

  const u16* gK = Kh + (b * NK + w * 16 + rr) * CD + h * HD + s * 8;
  const u16* gV = Vt + ((b * NH + h) * HD + w * 16 + rr) * NK + s * 8;
  uint4 kreg0, kreg1, vreg0, vreg1;
  kreg0 = *(const uint4*)(gK);
  kreg1 = *(const uint4*)(gK + 8 * CD);
  vreg0 = *(const uint4*)(gV);
  vreg1 = *(const uint4*)(gV + 8 * NK);

  f32x4 oacc[2][4] = {};
  f32x4 lacc[2] = {};

  for (int j0 = 0; j0 < NK; j0 += 64) {
    __syncthreads();
    *(uint4*)&Ks[(w * 16 + rr) * LSTR + s * 8] = kreg0;
    *(uint4*)&Ks[(w * 16 + 8 + rr) * LSTR + s * 8] = kreg1;
    *(uint4*)&Vs[(w * 16 + rr) * LSTR + s * 8] = vreg0;
    *(uint4*)&Vs[(w * 16 + 8 + rr) * LSTR + s * 8] = vreg1;
    __syncthreads();
    if (j0 + 64 < NK) {
      kreg0 = *(const uint4*)(gK + (j0 + 64) * CD);
      kreg1 = *(const uint4*)(gK + (j0 + 64) * CD + 8 * CD);
      vreg0 = *(const uint4*)(gV + j0 + 64);
      vreg1 = *(const uint4*)(gV + 8 * NK + j0 + 64);
    }

    f32x4 st[2][4] = {};
#pragma unroll
    for (int mi = 0; mi < 4; ++mi) {
      bf16x8 k0f = *(const bf16x8*)&Ks[(mi * 16 + lc) * LSTR + lq * 8];
      bf16x8 k1f = *(const bf16x8*)&Ks[(mi * 16 + lc) * LSTR + 32 + lq * 8];
#pragma unroll
      for (int ni = 0; ni < 2; ++ni) {
        st[ni][mi] = __builtin_amdgcn_mfma_f32_16x16x32_bf16(k0f, qf[ni][0], st[ni][mi], 0, 0, 0);
        st[ni][mi] = __builtin_amdgcn_mfma_f32_16x16x32_bf16(k1f, qf[ni][1], st[ni][mi], 0, 0, 0);
      }
    }
#pragma unroll
    for (int ni = 0; ni < 2; ++ni)
#pragma unroll
      for (int mi = 0; mi < 4; ++mi) {
        u32 e0 = __float_as_uint(__builtin_amdgcn_exp2f(st[ni][mi][0])) + 0x8000u;
        u32 e1 = __float_as_uint(__builtin_amdgcn_exp2f(st[ni][mi][1])) + 0x8000u;
        u32 e2 = __float_as_uint(__builtin_amdgcn_exp2f(st[ni][mi][2])) + 0x8000u;
        u32 e3 = __float_as_uint(__builtin_amdgcn_exp2f(st[ni][mi][3])) + 0x8000u;
        uint2 pk;
        pk.x = __builtin_amdgcn_perm(e1, e0, 0x07060302u);
        pk.y = __builtin_amdgcn_perm(e3, e2, 0x07060302u);
        *(uint2*)&QPs[(w * 32 + ni * 16 + lc) * LSTR + mi * 16 + lq * 4] = pk;
      }
#pragma unroll
    for (int kc = 0; kc < 2; ++kc) {
      bf16x8 pf[2], vf[4];
#pragma unroll
      for (int ni = 0; ni < 2; ++ni)
        pf[ni] = *(const bf16x8*)&QPs[(w * 32 + ni * 16 + lc) * LSTR + kc * 32 + lq * 8];
#pragma unroll
      for (int di = 0; di < 4; ++di)
        vf[di] = *(const bf16x8*)&Vs[(di * 16 + lc) * LSTR + kc * 32 + lq * 8];
#pragma unroll
      for (int ni = 0; ni < 2; ++ni) {
#pragma unroll
        for (int di = 0; di < 4; ++di)
          oacc[ni][di] = __builtin_amdgcn_mfma_f32_16x16x32_bf16(pf[ni], vf[di], oacc[ni][di], 0, 0, 0);
        lacc[ni] = __builtin_amdgcn_mfma_f32_16x16x32_bf16(pf[ni], ones, lacc[ni], 0, 0, 0);
      }
    }
  }
#pragma unroll
  for (int ni = 0; ni < 2; ++ni)
#pragma unroll
    for (int r = 0; r < 4; ++r) {
      float inv = 1.0f / lacc[ni][r];
#pragma unroll
      for (int di = 0; di < 4; ++di) {
        int row = qt * 128 + w * 32 + ni * 16 + lq * 4 + r;
        int col = h * HD + di * 16 + lc;
        AO[(b * NQ + row) * CD + col] = f2bf(oacc[ni][di][r] * inv);
      }
    }
}

extern "C" void kernel_launch(void* const* d_in, const int* in_sizes, int n_in,
                              void* d_out, int out_size, void* d_ws, size_t ws_size,
                              hipStream_t stream) {
  const float* q  = (const float*)d_in[0];
  const float* k  = (const float*)d_in[1];
  const float* v  = (const float*)d_in[2];
  const float* Wq = (const float*)d_in[3];
  const float* bq = (const float*)d_in[4];
  const float* Wk = (const float*)d_in[5];
  const float* bk = (const float*)d_in[6];
  const float* Wv = (const float*)d_in[7];
  const float* bv = (const float*)d_in[8];
  const float* Wo = (const float*)d_in[9];
  const float* bo = (const float*)d_in[10];

  char* ws = (char*)d_ws;
  size_t off = 0;
  auto alloc = [&](size_t bytes) {
    char* p = ws + off;
    off += (bytes + 255) & ~(size_t)255;
    return p;
  };
  u16* qb  = (u16*)alloc((size_t)B_ * NQ * CD * 2);
  u16* kb  = (u16*)alloc((size_t)B_ * NK * CD * 2);
  u16* vb  = (u16*)alloc((size_t)B_ * NK * CD * 2);
  u16* wqt = (u16*)alloc((size_t)CD * CD * 2);
  u16* wkt = (u16*)alloc((size_t)CD * CD * 2);
  u16* wvt = (u16*)alloc((size_t)CD * CD * 2);
  u16* wot = (u16*)alloc((size_t)CD * CD * 2);
  u16* Qh  = (u16*)alloc((size_t)B_ * NQ * CD * 2);
  u16* Kh  = (u16*)alloc((size_t)B_ * NK * CD * 2);
  u16* Vt  = (u16*)alloc((size_t)B_ * NK * CD * 2);
  u16* AO  = (u16*)alloc((size_t)B_ * NQ * CD * 2);

  prep_kernel<<<dim3(4224, 4), 256, 0, stream>>>(q, k, v, qb, kb, vb,
                                                 Wq, Wk, Wv, Wo, wqt, wkt, wvt, wot);
  gemm_qkv<<<dim3(8, 33, 3), 256, 0, stream>>>(qb, kb, vb, wqt, wkt, wvt, bq, bk, bv, Qh, Kh, Vt);
  attn_kernel<<<dim3(16, NH, B_), 256, 0, stream>>>(Qh, Kh, Vt, AO);
  gemm_o<<<dim3(16, 32), 256, 0, stream>>>(AO, wot, bo, (float*)d_out);
}